// Round 12
// baseline (99.802 us; speedup 1.0000x reference)
//
#include <hip/hip_runtime.h>
#include <stdint.h>

// Problem constants (from reference setup_inputs)
#define BB    8
#define NN    16384
#define KK    1024
#define KNN   16
#define QTR   (NN / 4)    // each of 4 waves per block owns a quarter of points
#define QGRP  (QTR / 4)   // float4-groups (4 pts) per quarter = 1024
#define PGRP  256         // pilot groups per quarter (= 1024 pts)
#define HCAP  96          // survivor slots per (center, quarter); mean ~19

typedef unsigned long long u64;

// Manual 64-bit shuffle-xor (two 32-bit shuffles).
__device__ __forceinline__ u64 shfl_xor_u64(u64 v, int mask) {
    int lo = (int)(uint32_t)v;
    int hi = (int)(uint32_t)(v >> 32);
    lo = __shfl_xor(lo, mask, 64);
    hi = __shfl_xor(hi, mask, 64);
    return ((u64)(uint32_t)hi << 32) | (u64)(uint32_t)lo;
}

// Butterfly min over all 64 lanes; every lane ends with the wave minimum.
__device__ __forceinline__ u64 wave_min_u64(u64 v) {
#pragma unroll
    for (int off = 32; off > 0; off >>= 1) {
        u64 o = shfl_xor_u64(v, off);
        v = o < v ? o : v;
    }
    return v;
}

// EXACT reference d2 (final ranking + fallback): cross = sequential FMA chain
// (einsum -> dot_general -> BLAS microkernel semantics, verified R3);
// x_sq/c_sq plain non-FMA reduce, elementwise ops left-to-right.
__device__ __forceinline__ float point_d2(const float* xb, int i,
                                          float c0, float c1, float c2, float csq) {
#pragma clang fp contract(off)
    float x0 = xb[i * 3 + 0];
    float x1 = xb[i * 3 + 1];
    float x2 = xb[i * 3 + 2];
    float xsq = (x0 * x0 + x1 * x1) + x2 * x2;
    float cross = __fmaf_rn(x2, c2, __fmaf_rn(x1, c1, x0 * c0));
    float d2 = (xsq + csq) - 2.0f * cross;
    return d2 < 0.0f ? 0.0f : d2;   // jnp.maximum(d2, 0)
}

// Cold-path exact fallback (full-N bubble scan), only on cap overflow.
__device__ __attribute__((noinline)) int fallback_scan(const float* xb,
                                                       float c0, float c1, float c2,
                                                       float csq, int lane) {
    u64 list[KNN];
#pragma unroll
    for (int j = 0; j < KNN; ++j) list[j] = ~0ull;
    for (int i = lane; i < NN; i += 64) {
        float d2 = point_d2(xb, i, c0, c1, c2, csq);
        float dist = __fsqrt_rn(d2);
        u64 key = ((u64)__float_as_uint(dist) << 32) | (u64)(uint32_t)i;
        if (key < list[KNN - 1]) {
#pragma unroll
            for (int j = 0; j < KNN; ++j) {
                bool lt = key < list[j];
                u64 lo = lt ? key : list[j];
                u64 hi = lt ? list[j] : key;
                list[j] = lo;
                key = hi;
            }
        }
    }
    int res = 0;
    for (int it = 0; it < KNN; ++it) {
        u64 best = wave_min_u64(list[0]);
        if (it == lane) res = (int)(uint32_t)best;
        if (list[0] == best) {
#pragma unroll
            for (int j = 0; j < KNN - 1; ++j) list[j] = list[j + 1];
            list[KNN - 1] = ~0ull;
        }
    }
    return res;
}

// 16th-smallest FLOAT of the 64 lane values via f32 bitonic sort across
// lanes (fminf/fmaxf compare-exchange: 1 shfl + 2 VALU per stage, vs 2 shfl
// + 3 VALU for the old u64 sortable-bits version). No tiebreak needed: a
// tied value is still a real point's d', so T stays a valid bound. Lane 15
// of the ascending sort holds the answer. All inputs finite (no NaN).
__device__ __forceinline__ float sixteenth_smallest(float m, int lane) {
#pragma unroll
    for (int k = 2; k <= 64; k <<= 1) {
#pragma unroll
        for (int j = k >> 1; j > 0; j >>= 1) {
            float o = __shfl_xor(m, j, 64);
            bool up = (lane & k) == 0;          // k=64: ascending
            bool takeMin = ((lane & j) == 0) == up;
            float mn = fminf(m, o);
            float mx = fmaxf(m, o);
            m = takeMin ? mn : mx;
        }
    }
    return __shfl(m, 15, 64);
}

// Unpack a group of 4 points (3 float4 = 48 B) + their exact xs.
__device__ __forceinline__ void load_group(const float4* x4, int g,
                                           float (&px)[4], float (&py)[4],
                                           float (&pz)[4], float (&xs)[4]) {
#pragma clang fp contract(off)
    float4 f0 = x4[g * 3 + 0];
    float4 f1 = x4[g * 3 + 1];
    float4 f2 = x4[g * 3 + 2];
    px[0] = f0.x; py[0] = f0.y; pz[0] = f0.z;
    px[1] = f0.w; py[1] = f1.x; pz[1] = f1.y;
    px[2] = f1.z; py[2] = f1.w; pz[2] = f2.x;
    px[3] = f2.y; py[3] = f2.z; pz[3] = f2.w;
#pragma unroll
    for (int k = 0; k < 4; ++k)
        xs[k] = (px[k] * px[k] + py[k] * py[k]) + pz[k] * pz[k];  // non-FMA, exact
}

// Block = 4 waves owns FOUR consecutive centers; wave q scans quarter q for
// all four centers straight from xyz (3x dwordx4 per 4-point group, xs inline
// — verified R11). R12: f32 bitonic for the pilot selection + deeper unrolls
// (phase 1 full, phase 2 x4); __launch_bounds__(256,8) caps VGPR at 64 so
// occupancy stays 8 waves/SIMD.
//   Phase 1 (pilot): per-lane min of d' = xs - 2*x.c over the first PGRP
//     groups of the quarter; min-of-4-waves via LDS, one bitonic -> T.
//   Phase 2 (filter): d' <= U = T + |T|*1e-5 + 5e-4 (verified R5-R11);
//     divergent LDS-atomic compaction (verified R10).
//   Phase 3: wave q reranks center q (total <= 256 -> <= 4 keys/lane exact)
//     by the verified (sqrt_rn-dist bits, idx) u64 key; 16-round pop-merge.
__global__ __launch_bounds__(256, 8) void knn_kernel(const float* __restrict__ xyz,
                                                     const float* __restrict__ centers,
                                                     int* __restrict__ out) {
#pragma clang fp contract(off)
    const int q = (int)(threadIdx.x >> 6);    // wave in block = quarter = owned center
    const int lane = (int)(threadIdx.x & 63);
    const int cbase = (int)blockIdx.x * 4;    // global center id of center 0
    const int b = cbase >> 10;                // batch

    __shared__ float    s_min[4][256];        // [center][srcwave*64+lane] 4 KB
    __shared__ float    s_T[4];               // [center]
    __shared__ int      s_cnt[4][4];          // [center][quarter]
    __shared__ uint32_t s_idx[4][4][HCAP];    // [center][quarter][slot] 6 KB

    // folded center consts: n = -2*c (exact)
    const float n0[3] = { -2.0f * centers[(cbase + 0) * 3 + 0],
                          -2.0f * centers[(cbase + 0) * 3 + 1],
                          -2.0f * centers[(cbase + 0) * 3 + 2] };
    const float n1[3] = { -2.0f * centers[(cbase + 1) * 3 + 0],
                          -2.0f * centers[(cbase + 1) * 3 + 1],
                          -2.0f * centers[(cbase + 1) * 3 + 2] };
    const float n2[3] = { -2.0f * centers[(cbase + 2) * 3 + 0],
                          -2.0f * centers[(cbase + 2) * 3 + 1],
                          -2.0f * centers[(cbase + 2) * 3 + 2] };
    const float n3[3] = { -2.0f * centers[(cbase + 3) * 3 + 0],
                          -2.0f * centers[(cbase + 3) * 3 + 1],
                          -2.0f * centers[(cbase + 3) * 3 + 2] };

    const float* xb = xyz + (size_t)b * NN * 3;
    const float4* x4 = (const float4*)xb;     // batch base is 16B-aligned
    const int gbase = q * QGRP;               // first group of this quarter

    // ---- Phase 1: pilot minima over first PGRP groups of this quarter ----
    float m0 = __builtin_inff(), m1 = m0, m2 = m0, m3 = m0;
#pragma unroll
    for (int s = 0; s < PGRP / 64; ++s) {
        int g = gbase + s * 64 + lane;
        float px[4], py[4], pz[4], xs[4];
        load_group(x4, g, px, py, pz, xs);
#pragma unroll
        for (int k = 0; k < 4; ++k) {
            float d0 = __fmaf_rn(px[k], n0[0], __fmaf_rn(py[k], n0[1], __fmaf_rn(pz[k], n0[2], xs[k])));
            float d1 = __fmaf_rn(px[k], n1[0], __fmaf_rn(py[k], n1[1], __fmaf_rn(pz[k], n1[2], xs[k])));
            float d2 = __fmaf_rn(px[k], n2[0], __fmaf_rn(py[k], n2[1], __fmaf_rn(pz[k], n2[2], xs[k])));
            float d3 = __fmaf_rn(px[k], n3[0], __fmaf_rn(py[k], n3[1], __fmaf_rn(pz[k], n3[2], xs[k])));
            m0 = d0 < m0 ? d0 : m0;
            m1 = d1 < m1 ? d1 : m1;
            m2 = d2 < m2 ? d2 : m2;
            m3 = d3 < m3 ? d3 : m3;
        }
    }
    s_min[0][q * 64 + lane] = m0;
    s_min[1][q * 64 + lane] = m1;
    s_min[2][q * 64 + lane] = m2;
    s_min[3][q * 64 + lane] = m3;
    if (threadIdx.x < 16) s_cnt[threadIdx.x >> 2][threadIdx.x & 3] = 0;
    __syncthreads();
    {
        // wave q: per-lane min across the 4 source waves for center q, then
        // one bitonic. Each min-of-4 is still a single real point's d'.
        float v = fminf(fminf(s_min[q][lane], s_min[q][64 + lane]),
                        fminf(s_min[q][128 + lane], s_min[q][192 + lane]));
        float t = sixteenth_smallest(v, lane);
        if (lane == 0) s_T[q] = t;
    }
    __syncthreads();
    const float T0 = s_T[0], T1 = s_T[1], T2 = s_T[2], T3 = s_T[3];
    const float U0 = T0 + fabsf(T0) * 1e-5f + 5e-4f;
    const float U1 = T1 + fabsf(T1) * 1e-5f + 5e-4f;
    const float U2 = T2 + fabsf(T2) * 1e-5f + 5e-4f;
    const float U3 = T3 + fabsf(T3) * 1e-5f + 5e-4f;

    // ---- Phase 2: filter scan; divergent atomic compaction into LDS ----
#pragma unroll 4
    for (int s = 0; s < QGRP / 64; ++s) {
        int g = gbase + s * 64 + lane;
        float px[4], py[4], pz[4], xs[4];
        load_group(x4, g, px, py, pz, xs);
#pragma unroll
        for (int k = 0; k < 4; ++k) {
            float d0 = __fmaf_rn(px[k], n0[0], __fmaf_rn(py[k], n0[1], __fmaf_rn(pz[k], n0[2], xs[k])));
            float d1 = __fmaf_rn(px[k], n1[0], __fmaf_rn(py[k], n1[1], __fmaf_rn(pz[k], n1[2], xs[k])));
            float d2 = __fmaf_rn(px[k], n2[0], __fmaf_rn(py[k], n2[1], __fmaf_rn(pz[k], n2[2], xs[k])));
            float d3 = __fmaf_rn(px[k], n3[0], __fmaf_rn(py[k], n3[1], __fmaf_rn(pz[k], n3[2], xs[k])));
            int i = g * 4 + k;   // batch-local point index
            if (d0 <= U0) {
                int pos = atomicAdd(&s_cnt[0][q], 1);
                if (pos < HCAP) s_idx[0][q][pos] = (uint32_t)i;
            }
            if (d1 <= U1) {
                int pos = atomicAdd(&s_cnt[1][q], 1);
                if (pos < HCAP) s_idx[1][q][pos] = (uint32_t)i;
            }
            if (d2 <= U2) {
                int pos = atomicAdd(&s_cnt[2][q], 1);
                if (pos < HCAP) s_idx[2][q][pos] = (uint32_t)i;
            }
            if (d3 <= U3) {
                int pos = atomicAdd(&s_cnt[3][q], 1);
                if (pos < HCAP) s_idx[3][q][pos] = (uint32_t)i;
            }
        }
    }
    __syncthreads();

    // ---- Phase 3: wave q reranks center q exactly (no idle waves) ----
    const int cc = cbase + q;
    const float c0 = centers[cc * 3 + 0];
    const float c1 = centers[cc * 3 + 1];
    const float c2 = centers[cc * 3 + 2];
    const float csq = (c0 * c0 + c1 * c1) + c2 * c2;  // exact non-FMA reduce
    const int k0 = s_cnt[q][0], k1 = s_cnt[q][1], k2 = s_cnt[q][2], k3 = s_cnt[q][3];
    const int p1o = k0, p2o = k0 + k1, p3o = k0 + k1 + k2;
    const int total = p3o + k3;
    const bool ok = (k0 <= HCAP) & (k1 <= HCAP) & (k2 <= HCAP) & (k3 <= HCAP) &
                    (total <= 4 * 64);

    int res = 0;
    if (ok) {
        // Combined stream -> <= 4 keys/lane -> depth-4 list is exact.
        u64 l0 = ~0ull, l1 = ~0ull, l2 = ~0ull, l3 = ~0ull;
        for (int j = lane; j < total; j += 64) {
            int qq, off;
            if (j < p1o)      { qq = 0; off = j; }
            else if (j < p2o) { qq = 1; off = j - p1o; }
            else if (j < p3o) { qq = 2; off = j - p2o; }
            else              { qq = 3; off = j - p3o; }
            int idx = (int)s_idx[q][qq][off];
            float d2 = point_d2(xb, idx, c0, c1, c2, csq);
            u64 key = ((u64)__float_as_uint(__fsqrt_rn(d2)) << 32) | (u64)(uint32_t)idx;
            bool t;
            t = key < l0; { u64 lo = t ? key : l0, hi = t ? l0 : key; l0 = lo; key = hi; }
            t = key < l1; { u64 lo = t ? key : l1, hi = t ? l1 : key; l1 = lo; key = hi; }
            t = key < l2; { u64 lo = t ? key : l2, hi = t ? l2 : key; l2 = lo; key = hi; }
            t = key < l3; { u64 lo = t ? key : l3, hi = t ? l3 : key; l3 = lo; key = hi; }
        }
        for (int it = 0; it < KNN; ++it) {
            u64 best = wave_min_u64(l0);
            if (it == lane) res = (int)(uint32_t)best;
            if (l0 == best) { l0 = l1; l1 = l2; l2 = l3; l3 = ~0ull; }
        }
    } else {
        res = fallback_scan(xb, c0, c1, c2, csq, lane);
    }

    // out[b][rank][c_in_batch]
    if (lane < KNN) {
        out[((size_t)b * KNN + lane) * KK + (cc & 1023)] = res;
    }
}

extern "C" void kernel_launch(void* const* d_in, const int* in_sizes, int n_in,
                              void* d_out, int out_size, void* d_ws, size_t ws_size,
                              hipStream_t stream) {
    const float* xyz = (const float*)d_in[0];
    const float* centers = (const float*)d_in[1];
    int* out = (int*)d_out;
    (void)d_ws; (void)ws_size;

    const int nblocks = BB * KK / 4;   // 2048 blocks x 4 waves = 8192 waves (8/SIMD)
    hipLaunchKernelGGL(knn_kernel, dim3(nblocks), dim3(256), 0, stream,
                       xyz, centers, out);
}